// Round 1
// baseline (770.539 us; speedup 1.0000x reference)
//
#include <hip/hip_runtime.h>
#include <hip/hip_bf16.h>
#include <cstddef>

// ---------------------------------------------------------------------------
// Algebra: a_i = sigmoid(k_i . q_{b_i}) with k_i = x_i@Wk + bk, q_b = u_b@Wq + bq
//        = sigmoid( x_i . (Wk @ q_b) + bk . q_b )
// Precompute per-graph v_b = Wk @ q_b  [B,128] and c_b = bk . q_b  [B].
// Main pass: stream x once (512 MB, HBM-bound), gate + segment-sum into agg.
// Epilogue: out = concat(agg, u) @ Wu + bu.
// ---------------------------------------------------------------------------

// Kernel A: per-graph q, then v = Wk @ q and c = bk . q.
// One block (1 wave, 64 threads) per graph.
__global__ __launch_bounds__(64) void precompute_vc(
    const float* __restrict__ u, const float* __restrict__ Wq,
    const float* __restrict__ bq, const float* __restrict__ Wk,
    const float* __restrict__ bk, float* __restrict__ v, float* __restrict__ c) {
  const int b = blockIdx.x;
  const int h = threadIdx.x;  // 0..63
  __shared__ alignas(16) float us[128];
  __shared__ float qs[64];

  // stage u row (128 f32) into LDS
  float2 uu = *(const float2*)(u + (size_t)b * 128 + 2 * h);
  us[2 * h] = uu.x;
  us[2 * h + 1] = uu.y;
  __syncthreads();

  // q_h = bq_h + sum_d u_d * Wq[d,h]   (Wq reads coalesced across lanes)
  float q = bq[h];
  for (int d = 0; d < 128; d += 4) {
    float4 ud = *(const float4*)&us[d];
    q = fmaf(ud.x, Wq[(d + 0) * 64 + h], q);
    q = fmaf(ud.y, Wq[(d + 1) * 64 + h], q);
    q = fmaf(ud.z, Wq[(d + 2) * 64 + h], q);
    q = fmaf(ud.w, Wq[(d + 3) * 64 + h], q);
  }
  qs[h] = q;

  // c_b = sum_h q_h * bk_h (wave butterfly reduce)
  float pc = q * bk[h];
#pragma unroll
  for (int m = 32; m; m >>= 1) pc += __shfl_xor(pc, m);
  if (h == 0) c[b] = pc;
  __syncthreads();

  // v_d = sum_h q_h * Wk[d,h]; lane h covers d = h and d = h+64.
  // Wk rows are 64B-aligned; footprint 32KB -> L1-hot across the 16
  // blocks/CU that run serially.
  float v0 = 0.f, v1 = 0.f;
  const float* wk0 = Wk + (size_t)h * 64;
  const float* wk1 = Wk + (size_t)(h + 64) * 64;
  for (int hh = 0; hh < 64; ++hh) {
    float qv = qs[hh];
    v0 = fmaf(qv, wk0[hh], v0);
    v1 = fmaf(qv, wk1[hh], v1);
  }
  v[(size_t)b * 128 + h] = v0;
  v[(size_t)b * 128 + 64 + h] = v1;
}

// Main kernel: per-wave contiguous node chunk; batch is sorted so graph
// switches are rare (~1-2 per wave). Per node: 512B coalesced x-row load,
// dot with v_b, sigmoid gate, accumulate a*x into per-lane registers;
// atomicAdd flush only at segment boundaries.
#define TPB 256
#define WPB (TPB / 64)
__global__ __launch_bounds__(TPB) void gate_scatter(
    const float* __restrict__ x, const int* __restrict__ batch,
    const float* __restrict__ v, const float* __restrict__ c,
    float* __restrict__ agg, int N, int nwaves) {
  const int wave = blockIdx.x * WPB + (threadIdx.x >> 6);
  const int lane = threadIdx.x & 63;
  const int per = (N + nwaves - 1) / nwaves;
  const int start = wave * per;
  const int end = min(N, start + per);
  if (start >= end) return;

  int curb = batch[start];
  float2 vv = *(const float2*)(v + (size_t)curb * 128 + 2 * lane);
  float cb = c[curb];
  float a0 = 0.f, a1 = 0.f;

  for (int i = start; i < end; ++i) {
    const int b = batch[i];            // wave-uniform -> scalar load, L1-hot
    if (b != curb) {                   // wave-uniform branch, rare
      atomicAdd(&agg[(size_t)curb * 128 + 2 * lane], a0);
      atomicAdd(&agg[(size_t)curb * 128 + 2 * lane + 1], a1);
      a0 = 0.f;
      a1 = 0.f;
      curb = b;
      vv = *(const float2*)(v + (size_t)curb * 128 + 2 * lane);
      cb = c[curb];
    }
    const float2 xx = *(const float2*)(x + (size_t)i * 128 + 2 * lane);
    float p = fmaf(xx.x, vv.x, xx.y * vv.y);
    // full-wave butterfly: every lane ends with the row dot product
    p += __shfl_xor(p, 1);
    p += __shfl_xor(p, 2);
    p += __shfl_xor(p, 4);
    p += __shfl_xor(p, 8);
    p += __shfl_xor(p, 16);
    p += __shfl_xor(p, 32);
    const float z = p + cb;
    const float a = 1.0f / (1.0f + __expf(-z));
    a0 = fmaf(a, xx.x, a0);
    a1 = fmaf(a, xx.y, a1);
  }
  atomicAdd(&agg[(size_t)curb * 128 + 2 * lane], a0);
  atomicAdd(&agg[(size_t)curb * 128 + 2 * lane + 1], a1);
}

// Epilogue: out[b,:] = concat(agg[b,:], u[b,:]) @ Wu + bu.
// 8 graphs per block so each Wu load (coalesced, L2-resident) feeds 8 FMAs.
__global__ __launch_bounds__(128) void phi_u(
    const float* __restrict__ agg, const float* __restrict__ u,
    const float* __restrict__ Wu, const float* __restrict__ bu,
    float* __restrict__ out) {
  const int o = threadIdx.x;  // 0..127 output feature
  const int b0 = blockIdx.x * 8;
  __shared__ alignas(16) float s[8][256];
#pragma unroll
  for (int g = 0; g < 8; ++g) {
    s[g][o] = agg[(size_t)(b0 + g) * 128 + o];
    s[g][128 + o] = u[(size_t)(b0 + g) * 128 + o];
  }
  __syncthreads();

  float acc[8];
  const float bo = bu[o];
#pragma unroll
  for (int g = 0; g < 8; ++g) acc[g] = bo;

  for (int d = 0; d < 256; d += 4) {
    const float w0 = Wu[(size_t)(d + 0) * 128 + o];
    const float w1 = Wu[(size_t)(d + 1) * 128 + o];
    const float w2 = Wu[(size_t)(d + 2) * 128 + o];
    const float w3 = Wu[(size_t)(d + 3) * 128 + o];
#pragma unroll
    for (int g = 0; g < 8; ++g) {
      const float4 sv = *(const float4*)&s[g][d];  // LDS b128 broadcast
      acc[g] = fmaf(sv.x, w0, acc[g]);
      acc[g] = fmaf(sv.y, w1, acc[g]);
      acc[g] = fmaf(sv.z, w2, acc[g]);
      acc[g] = fmaf(sv.w, w3, acc[g]);
    }
  }
#pragma unroll
  for (int g = 0; g < 8; ++g) out[(size_t)(b0 + g) * 128 + o] = acc[g];
}

extern "C" void kernel_launch(void* const* d_in, const int* in_sizes, int n_in,
                              void* d_out, int out_size, void* d_ws, size_t ws_size,
                              hipStream_t stream) {
  // Input order: x, edge_index(unused), e(unused), u, batch, Wk, bk, Wq, bq, Wu, bu
  const float* x = (const float*)d_in[0];
  const float* u = (const float*)d_in[3];
  const int* batch = (const int*)d_in[4];  // harness converts int -> int32
  const float* Wk = (const float*)d_in[5];
  const float* bk = (const float*)d_in[6];
  const float* Wq = (const float*)d_in[7];
  const float* bq = (const float*)d_in[8];
  const float* Wu = (const float*)d_in[9];
  const float* bu = (const float*)d_in[10];
  float* out = (float*)d_out;

  const int N = in_sizes[0] / 128;  // 1,000,000
  const int B = in_sizes[3] / 128;  // 4096

  // Workspace layout: v [B*128] f32 | c [B] f32 | agg [B*128] f32  (~4.02 MB)
  char* ws = (char*)d_ws;
  float* v = (float*)ws;
  float* c = (float*)(ws + (size_t)B * 128 * 4);
  float* agg = (float*)(ws + (size_t)B * 128 * 4 + (size_t)B * 4);

  // ws is re-poisoned to 0xAA before every timed call: zero agg each launch.
  hipMemsetAsync(agg, 0, (size_t)B * 128 * 4, stream);

  precompute_vc<<<B, 64, 0, stream>>>(u, Wq, bq, Wk, bk, v, c);

  const int nwaves = 8192;  // ~123 nodes/wave; fully resident at low VGPR
  gate_scatter<<<nwaves / WPB, TPB, 0, stream>>>(x, batch, v, c, agg, N, nwaves);

  phi_u<<<B / 8, 128, 0, stream>>>(agg, u, Wu, bu, out);
}

// Round 2
// 722.729 us; speedup vs baseline: 1.0662x; 1.0662x over previous
//
#include <hip/hip_runtime.h>
#include <hip/hip_bf16.h>
#include <cstddef>

// ---------------------------------------------------------------------------
// Algebra: a_i = sigmoid(k_i . q_{b_i}) with k_i = x_i@Wk + bk, q_b = u_b@Wq + bq
//        = sigmoid( x_i . (Wk @ q_b) + bk . q_b )
// Kernel Q: per-graph q_b (coalesced Wq), c_b = bk.q_b, zero agg row.
// Kernel V: v = q @ Wk^T with Wk staged coalesced in LDS (fixes the round-1
//           uncoalesced Wk column reads that burned ~50+ us on the L1 port).
// gate_scatter: stream x once (512 MB -> HBM-bound floor ~85 us). 2 nodes per
//           wave-iteration via float4 (1 KB/load-instr), half-wave butterfly
//           (5 shfls / 2 nodes), explicit prefetch of next pair.
// phi_u:    out = concat(agg, u) @ Wu + bu.
// ---------------------------------------------------------------------------

// Kernel Q: one wave per graph. q[b][h], c[b], agg[b][:] = 0.
__global__ __launch_bounds__(64) void kq(
    const float* __restrict__ u, const float* __restrict__ Wq,
    const float* __restrict__ bq, const float* __restrict__ bk,
    float* __restrict__ q, float* __restrict__ c, float* __restrict__ agg) {
  const int b = blockIdx.x;
  const int h = threadIdx.x;  // 0..63
  __shared__ alignas(16) float us[128];

  float2 uu = *(const float2*)(u + (size_t)b * 128 + 2 * h);
  us[2 * h] = uu.x;
  us[2 * h + 1] = uu.y;
  __syncthreads();

  float acc = bq[h];
  for (int d = 0; d < 128; d += 4) {
    float4 ud = *(const float4*)&us[d];
    acc = fmaf(ud.x, Wq[(d + 0) * 64 + h], acc);
    acc = fmaf(ud.y, Wq[(d + 1) * 64 + h], acc);
    acc = fmaf(ud.z, Wq[(d + 2) * 64 + h], acc);
    acc = fmaf(ud.w, Wq[(d + 3) * 64 + h], acc);
  }
  q[(size_t)b * 64 + h] = acc;

  float pc = acc * bk[h];
#pragma unroll
  for (int m = 32; m; m >>= 1) pc += __shfl_xor(pc, m);
  if (h == 0) c[b] = pc;

  // zero this graph's agg row (replaces the separate memset launch)
  *(float2*)(agg + (size_t)b * 128 + 2 * h) = make_float2(0.f, 0.f);
}

// Kernel V: v[b][d] = sum_h q[b][h] * Wk[d][h], 16 graphs per block.
// Wk (32 KB) staged coalesced into LDS with stride-65 padding -> the per-lane
// column reads become 2-way-free LDS reads instead of 64-line L1 gathers.
__global__ __launch_bounds__(128) void kv(
    const float* __restrict__ Wk, const float* __restrict__ q,
    float* __restrict__ v) {
  const int t = threadIdx.x;   // 0..127
  const int g0 = blockIdx.x * 16;
  __shared__ float wk[128 * 65];            // [d][h] stride 65, 33.3 KB
  __shared__ alignas(16) float qs[64 * 20]; // [h][g] stride 20, 5 KB

  // stage Wk coalesced (float4; row length 64 keeps d constant per quad)
  for (int j = 0; j < 16; ++j) {
    const int idx = (j * 128 + t) * 4;  // element index, multiple of 4
    const float4 w4 = *(const float4*)(Wk + idx);
    const int d = idx >> 6;
    const int hh = idx & 63;
    wk[d * 65 + hh + 0] = w4.x;
    wk[d * 65 + hh + 1] = w4.y;
    wk[d * 65 + hh + 2] = w4.z;
    wk[d * 65 + hh + 3] = w4.w;
  }
  // stage q transposed: qs[h][g]
  for (int j = 0; j < 8; ++j) {
    const int idx = j * 128 + t;  // 0..1023
    const int g = idx >> 6;
    const int hh = idx & 63;
    qs[hh * 20 + g] = q[(size_t)(g0 + g) * 64 + hh];
  }
  __syncthreads();

  const int o = t;  // output feature d, 0..127
  float acc[16];
#pragma unroll
  for (int g = 0; g < 16; ++g) acc[g] = 0.f;

  for (int hh = 0; hh < 64; ++hh) {
    const float w = wk[o * 65 + hh];  // bank (o+hh)%32 -> 2-way, free
    const float4 q0 = *(const float4*)&qs[hh * 20 + 0];   // broadcast
    const float4 q1 = *(const float4*)&qs[hh * 20 + 4];
    const float4 q2 = *(const float4*)&qs[hh * 20 + 8];
    const float4 q3 = *(const float4*)&qs[hh * 20 + 12];
    acc[0] = fmaf(w, q0.x, acc[0]);   acc[1] = fmaf(w, q0.y, acc[1]);
    acc[2] = fmaf(w, q0.z, acc[2]);   acc[3] = fmaf(w, q0.w, acc[3]);
    acc[4] = fmaf(w, q1.x, acc[4]);   acc[5] = fmaf(w, q1.y, acc[5]);
    acc[6] = fmaf(w, q1.z, acc[6]);   acc[7] = fmaf(w, q1.w, acc[7]);
    acc[8] = fmaf(w, q2.x, acc[8]);   acc[9] = fmaf(w, q2.y, acc[9]);
    acc[10] = fmaf(w, q2.z, acc[10]); acc[11] = fmaf(w, q2.w, acc[11]);
    acc[12] = fmaf(w, q3.x, acc[12]); acc[13] = fmaf(w, q3.y, acc[13]);
    acc[14] = fmaf(w, q3.z, acc[14]); acc[15] = fmaf(w, q3.w, acc[15]);
  }
#pragma unroll
  for (int g = 0; g < 16; ++g) v[(size_t)(g0 + g) * 128 + o] = acc[g];
}

// Main kernel: 2 nodes per wave-iteration. Lane layout: half = lane>>5 picks
// node i+half; each half-wave's 32 lanes cover the 128 features as float4.
// 5-step half-wave butterfly gives each half its node's full dot product.
#define TPB 256
#define WPB (TPB / 64)
#define PER 124  // even chunk per wave
__global__ __launch_bounds__(TPB) void gate_scatter(
    const float* __restrict__ x, const int* __restrict__ batch,
    const float* __restrict__ v, const float* __restrict__ c,
    float* __restrict__ agg, int N) {
  const int wave = blockIdx.x * WPB + (threadIdx.x >> 6);
  const int lane = threadIdx.x & 63;
  const int half = lane >> 5;
  const int col4 = (lane & 31) * 4;
  const int start = wave * PER;
  if (start >= N) return;
  const int end = min(N, start + PER);

  int idx0 = min(start + half, end - 1);
  int bcur = batch[idx0];
  const float* xptr = x + (size_t)(start + half) * 128 + col4;
  float4 xx = (start + half < end) ? *(const float4*)xptr
                                   : make_float4(0.f, 0.f, 0.f, 0.f);
  int curb = bcur;
  float4 vv = *(const float4*)(v + (size_t)curb * 128 + col4);
  float cb = c[curb];
  float4 acc = make_float4(0.f, 0.f, 0.f, 0.f);

  for (int i = start; i < end; i += 2) {
    // ---- prefetch next pair (overlaps the shfl/exp chain below) ----
    const int ni = i + 2;
    float4 xn = make_float4(0.f, 0.f, 0.f, 0.f);
    int bn = bcur;
    if (ni < end) {
      bn = batch[min(ni + half, end - 1)];
      if (ni + half < end) xn = *(const float4*)(xptr + 256);
    }
    // ---- segment boundary (wave-uniform rare branch) ----
    if (__any(bcur != curb)) {
      atomicAdd(&agg[(size_t)curb * 128 + col4 + 0], acc.x);
      atomicAdd(&agg[(size_t)curb * 128 + col4 + 1], acc.y);
      atomicAdd(&agg[(size_t)curb * 128 + col4 + 2], acc.z);
      atomicAdd(&agg[(size_t)curb * 128 + col4 + 3], acc.w);
      acc = make_float4(0.f, 0.f, 0.f, 0.f);
      curb = bcur;
      vv = *(const float4*)(v + (size_t)curb * 128 + col4);
      cb = c[curb];
    }
    // ---- gate + accumulate ----
    float p = fmaf(xx.x, vv.x, fmaf(xx.y, vv.y, fmaf(xx.z, vv.z, xx.w * vv.w)));
    p += __shfl_xor(p, 1);
    p += __shfl_xor(p, 2);
    p += __shfl_xor(p, 4);
    p += __shfl_xor(p, 8);
    p += __shfl_xor(p, 16);  // masks < 32: stays within the half
    const float a = 1.0f / (1.0f + __expf(-(p + cb)));
    acc.x = fmaf(a, xx.x, acc.x);
    acc.y = fmaf(a, xx.y, acc.y);
    acc.z = fmaf(a, xx.z, acc.z);
    acc.w = fmaf(a, xx.w, acc.w);
    xx = xn;
    bcur = bn;
    xptr += 256;
  }
  atomicAdd(&agg[(size_t)curb * 128 + col4 + 0], acc.x);
  atomicAdd(&agg[(size_t)curb * 128 + col4 + 1], acc.y);
  atomicAdd(&agg[(size_t)curb * 128 + col4 + 2], acc.z);
  atomicAdd(&agg[(size_t)curb * 128 + col4 + 3], acc.w);
}

// Epilogue: out[b,:] = concat(agg[b,:], u[b,:]) @ Wu + bu, 8 graphs/block.
__global__ __launch_bounds__(128) void phi_u(
    const float* __restrict__ agg, const float* __restrict__ u,
    const float* __restrict__ Wu, const float* __restrict__ bu,
    float* __restrict__ out) {
  const int o = threadIdx.x;  // 0..127 output feature
  const int b0 = blockIdx.x * 8;
  __shared__ alignas(16) float s[8][256];
#pragma unroll
  for (int g = 0; g < 8; ++g) {
    s[g][o] = agg[(size_t)(b0 + g) * 128 + o];
    s[g][128 + o] = u[(size_t)(b0 + g) * 128 + o];
  }
  __syncthreads();

  float acc[8];
  const float bo = bu[o];
#pragma unroll
  for (int g = 0; g < 8; ++g) acc[g] = bo;

  for (int d = 0; d < 256; d += 4) {
    const float w0 = Wu[(size_t)(d + 0) * 128 + o];
    const float w1 = Wu[(size_t)(d + 1) * 128 + o];
    const float w2 = Wu[(size_t)(d + 2) * 128 + o];
    const float w3 = Wu[(size_t)(d + 3) * 128 + o];
#pragma unroll
    for (int g = 0; g < 8; ++g) {
      const float4 sv = *(const float4*)&s[g][d];
      acc[g] = fmaf(sv.x, w0, acc[g]);
      acc[g] = fmaf(sv.y, w1, acc[g]);
      acc[g] = fmaf(sv.z, w2, acc[g]);
      acc[g] = fmaf(sv.w, w3, acc[g]);
    }
  }
#pragma unroll
  for (int g = 0; g < 8; ++g) out[(size_t)(b0 + g) * 128 + o] = acc[g];
}

extern "C" void kernel_launch(void* const* d_in, const int* in_sizes, int n_in,
                              void* d_out, int out_size, void* d_ws, size_t ws_size,
                              hipStream_t stream) {
  // Input order: x, edge_index(unused), e(unused), u, batch, Wk, bk, Wq, bq, Wu, bu
  const float* x = (const float*)d_in[0];
  const float* u = (const float*)d_in[3];
  const int* batch = (const int*)d_in[4];
  const float* Wk = (const float*)d_in[5];
  const float* bk = (const float*)d_in[6];
  const float* Wq = (const float*)d_in[7];
  const float* bq = (const float*)d_in[8];
  const float* Wu = (const float*)d_in[9];
  const float* bu = (const float*)d_in[10];
  float* out = (float*)d_out;

  const int N = in_sizes[0] / 128;  // 1,000,000
  const int B = in_sizes[3] / 128;  // 4096

  // Workspace: q [B*64] | v [B*128] | c [B] | agg [B*128]  (~3.1 MB)
  char* ws = (char*)d_ws;
  float* q = (float*)ws;
  float* v = (float*)(ws + (size_t)B * 64 * 4);
  float* c = (float*)(ws + (size_t)B * 64 * 4 + (size_t)B * 128 * 4);
  float* agg = (float*)(ws + (size_t)B * 64 * 4 + (size_t)B * 128 * 4 + (size_t)B * 4);

  kq<<<B, 64, 0, stream>>>(u, Wq, bq, bk, q, c, agg);
  kv<<<B / 16, 128, 0, stream>>>(Wk, q, v);

  const int nwaves = (N + PER - 1) / PER;
  const int nblocks = (nwaves + WPB - 1) / WPB;
  gate_scatter<<<nblocks, TPB, 0, stream>>>(x, batch, v, c, agg, N);

  phi_u<<<B / 8, 128, 0, stream>>>(agg, u, Wu, bu, out);
}